// Round 1
// baseline (1986.331 us; speedup 1.0000x reference)
//
#include <hip/hip_runtime.h>

// ---------------------------------------------------------------------------
// GCN 3-layer forward on MI355X. f32 baseline.
// out[d] = relu( dinv[d] * ( sum_{s->d} g[s] + g[d] ) + b ),  g = (x@W)*dinv
// ---------------------------------------------------------------------------

__global__ void k_deg_init(float* __restrict__ deg, int N) {
    int i = blockIdx.x * blockDim.x + threadIdx.x;
    if (i < N) deg[i] = 1.0f;  // self-loop
}

__global__ void k_deg_count(const int* __restrict__ dst, float* __restrict__ deg, int E) {
    int i = blockIdx.x * blockDim.x + threadIdx.x;
    int stride = gridDim.x * blockDim.x;
    for (; i < E; i += stride) atomicAdd(&deg[dst[i]], 1.0f);
}

__global__ void k_rsqrt(float* __restrict__ deg, int N) {
    int i = blockIdx.x * blockDim.x + threadIdx.x;
    if (i < N) deg[i] = rsqrtf(deg[i]);  // deg >= 1 always (self-loop)
}

// g[n] = (x[row(n)] @ W) * dinv[n]; also writes T init (self-loop term).
// One wave handles 64/OF nodes; lane -> output column.
// W staged in LDS [KF][OF]: lanes read consecutive cols -> 2-way alias (free).
// NOTE: T may alias X (in-place row reuse). Safe: a row is read only by the
// wave that writes it, and the store value depends on all its loads.
template <int KF, int OF>
__global__ __launch_bounds__(256) void k_gemm(
    const float* __restrict__ X, int sx,
    const int* __restrict__ nodes,  // may be null (identity)
    const float* __restrict__ W,    // [KF][OF]
    const float* __restrict__ dinv,
    float* __restrict__ G,          // [N][OF] packed
    float* T, int st,               // stride-st rows (64)
    int N)
{
    __shared__ float Wl[KF * OF];
    for (int i = threadIdx.x; i < KF * OF; i += blockDim.x) Wl[i] = W[i];
    __syncthreads();

    constexpr int NPW = 64 / OF;      // nodes per wave
    const int lane = threadIdx.x & 63;
    const int sub  = lane / OF;
    const int col  = lane % OF;
    const int wid  = (blockIdx.x * blockDim.x + threadIdx.x) >> 6;

    long n = (long)wid * NPW + sub;
    if (n >= N) return;
    long row = nodes ? (long)nodes[n] : n;
    const float* xr = X + row * (long)sx;

    float acc = 0.0f;
#pragma unroll 8
    for (int k = 0; k < KF; k += 4) {
        float4 xv = *reinterpret_cast<const float4*>(xr + k);
        acc = fmaf(xv.x, Wl[(k + 0) * OF + col], acc);
        acc = fmaf(xv.y, Wl[(k + 1) * OF + col], acc);
        acc = fmaf(xv.z, Wl[(k + 2) * OF + col], acc);
        acc = fmaf(xv.w, Wl[(k + 3) * OF + col], acc);
    }
    float gv = acc * dinv[n];
    G[n * OF + col] = gv;
    T[n * (long)st + col] = gv;
}

// For each edge s->d: t[d][f] += g[s][f].  Wave handles 64/F edges,
// lanes within an F-group do a coalesced 4*F-byte gather + atomic add.
template <int F>
__global__ __launch_bounds__(256) void k_edge_agg(
    const int* __restrict__ src, const int* __restrict__ dst,
    const float* __restrict__ g, float* __restrict__ t, int st, int E)
{
    constexpr int EPW = 64 / F;  // edges per wave
    const int lane = threadIdx.x & 63;
    const int sub  = lane / F;
    const int f    = lane % F;
    const int wid  = (blockIdx.x * (blockDim.x >> 6)) + (threadIdx.x >> 6);
    const int nw   = gridDim.x * (blockDim.x >> 6);

    for (long e0 = (long)wid * EPW; e0 < E; e0 += (long)nw * EPW) {
        long e = e0 + sub;
        if (e < E) {
            int s = src[e];
            int d = dst[e];
            float v = g[(long)s * F + f];
            atomicAdd(&t[(long)d * st + f], v);
        }
    }
}

// y[n][f] = relu(t[n][f]*dinv[n] + b[f]); may run in place (y==t).
template <int F>
__global__ __launch_bounds__(256) void k_epi(
    const float* T, int st,
    const float* __restrict__ dinv, const float* __restrict__ b,
    float* Y, int sy, int N)
{
    long total = (long)N * F;
    long i = (long)blockIdx.x * blockDim.x + threadIdx.x;
    long stride = (long)gridDim.x * blockDim.x;
    for (; i < total; i += stride) {
        long n = i / F;
        int  f = (int)(i - n * F);
        float v = fmaf(T[n * (long)st + f], dinv[n], b[f]);
        Y[n * (long)sy + f] = fmaxf(v, 0.0f);
    }
}

extern "C" void kernel_launch(void* const* d_in, const int* in_sizes, int n_in,
                              void* d_out, int out_size, void* d_ws, size_t ws_size,
                              hipStream_t stream) {
    const int*   nodes = (const int*)d_in[0];
    const int*   edges = (const int*)d_in[1];
    const float* emb   = (const float*)d_in[2];
    const float* W1    = (const float*)d_in[3];
    const float* b1    = (const float*)d_in[4];
    const float* W2    = (const float*)d_in[5];
    const float* b2    = (const float*)d_in[6];
    const float* W3    = (const float*)d_in[7];
    const float* b3    = (const float*)d_in[8];

    const int N = in_sizes[0];
    const int E = in_sizes[1] / 2;
    const int* src = edges;
    const int* dstv = edges + E;

    char* ws = (char*)d_ws;
    float* dinv = (float*)(ws);                   // N floats (400 KB)
    float* A    = (float*)(ws + (1u  << 20));     // G: up to N*64 f32 (25.6 MB)
    float* B    = (float*)(ws + (28u << 20));     // T / x_next: N*64 f32, stride 64
    float* out  = (float*)d_out;

    const int nbN = (N + 255) / 256;

    // --- degree / dinv (shared by all 3 layers) ---
    hipLaunchKernelGGL(k_deg_init,  dim3(nbN),  dim3(256), 0, stream, dinv, N);
    hipLaunchKernelGGL(k_deg_count, dim3(2048), dim3(256), 0, stream, dstv, dinv, E);
    hipLaunchKernelGGL(k_rsqrt,     dim3(nbN),  dim3(256), 0, stream, dinv, N);

    // --- layer 1: 256 -> 64 ---
    {
        int waves = N;  // 1 node / wave
        int blocks = (waves + 3) / 4;
        hipLaunchKernelGGL((k_gemm<256, 64>), dim3(blocks), dim3(256), 0, stream,
                           emb, 256, nodes, W1, dinv, A, B, 64, N);
        hipLaunchKernelGGL((k_edge_agg<64>), dim3(4096), dim3(256), 0, stream,
                           src, dstv, A, B, 64, E);
        hipLaunchKernelGGL((k_epi<64>), dim3(2048), dim3(256), 0, stream,
                           B, 64, dinv, b1, B, 64, N);
    }
    // --- layer 2: 64 -> 32 ---
    {
        int waves = (N + 1) / 2;  // 2 nodes / wave
        int blocks = (waves + 3) / 4;
        hipLaunchKernelGGL((k_gemm<64, 32>), dim3(blocks), dim3(256), 0, stream,
                           B, 64, (const int*)nullptr, W2, dinv, A, B, 64, N);
        hipLaunchKernelGGL((k_edge_agg<32>), dim3(4096), dim3(256), 0, stream,
                           src, dstv, A, B, 64, E);
        hipLaunchKernelGGL((k_epi<32>), dim3(2048), dim3(256), 0, stream,
                           B, 64, dinv, b2, B, 64, N);
    }
    // --- layer 3: 32 -> 16 ---
    {
        int waves = (N + 3) / 4;  // 4 nodes / wave
        int blocks = (waves + 3) / 4;
        hipLaunchKernelGGL((k_gemm<32, 16>), dim3(blocks), dim3(256), 0, stream,
                           B, 64, (const int*)nullptr, W3, dinv, A, B, 64, N);
        hipLaunchKernelGGL((k_edge_agg<16>), dim3(4096), dim3(256), 0, stream,
                           src, dstv, A, B, 64, E);
        hipLaunchKernelGGL((k_epi<16>), dim3(2048), dim3(256), 0, stream,
                           B, 64, dinv, b3, out, 16, N);
    }
}

// Round 2
// 758.882 us; speedup vs baseline: 2.6174x; 2.6174x over previous
//
#include <hip/hip_runtime.h>

// ---------------------------------------------------------------------------
// 3-layer GCN forward. out[d] = relu( dinv[d]*( sum_{s->d} g[s] + g[d] ) + b ),
// g = (x@W)*dinv.  CSR (sorted-by-dst) built once per call; no float atomics.
// ---------------------------------------------------------------------------

__global__ void k_zero_i(int* __restrict__ p, int n) {
    int i = blockIdx.x * blockDim.x + threadIdx.x;
    if (i < n) p[i] = 0;
}

__global__ void k_hist(const int* __restrict__ dst, int* __restrict__ cnt, int E) {
    int i = blockIdx.x * blockDim.x + threadIdx.x;
    int st = gridDim.x * blockDim.x;
    for (; i < E; i += st) atomicAdd(&cnt[dst[i]], 1);
}

// per-256-block inclusive scan of cnt -> row1[i] (= row_off[i+1]); block totals
__global__ __launch_bounds__(256) void k_scanA(const int* __restrict__ cnt,
                                               int* __restrict__ row1,
                                               int* __restrict__ bsum, int N) {
    __shared__ int s[256];
    int t = threadIdx.x;
    int i = blockIdx.x * 256 + t;
    int v = (i < N) ? cnt[i] : 0;
    s[t] = v; __syncthreads();
    for (int off = 1; off < 256; off <<= 1) {
        int a = (t >= off) ? s[t - off] : 0;
        __syncthreads();
        s[t] += a;
        __syncthreads();
    }
    if (i < N) row1[i] = s[t];
    if (t == 255) bsum[blockIdx.x] = s[255];
}

// exclusive scan of bsum[nb] in place (nb <= 1024)
__global__ __launch_bounds__(1024) void k_scanB(int* __restrict__ bs, int nb) {
    __shared__ int s[1024];
    int t = threadIdx.x;
    int v = (t < nb) ? bs[t] : 0;
    s[t] = v; __syncthreads();
    for (int off = 1; off < 1024; off <<= 1) {
        int a = (t >= off) ? s[t - off] : 0;
        __syncthreads();
        s[t] += a;
        __syncthreads();
    }
    if (t < nb) bs[t] = s[t] - v;  // exclusive
}

// finalize row_off, init cursor (= final row starts)
__global__ void k_scanC(int* __restrict__ row_off, const int* __restrict__ boff,
                        int* __restrict__ cur, int N) {
    int i = blockIdx.x * blockDim.x + threadIdx.x;
    if (i < N) {
        int v = row_off[i + 1] + boff[i >> 8];
        row_off[i + 1] = v;
        if (i + 1 < N) cur[i + 1] = v;
        if (i == 0) { row_off[0] = 0; cur[0] = 0; }
    }
}

__global__ void k_scatter(const int* __restrict__ src, const int* __restrict__ dst,
                          int* __restrict__ cur, int* __restrict__ esrc, int E) {
    int i = blockIdx.x * blockDim.x + threadIdx.x;
    int st = gridDim.x * blockDim.x;
    for (; i < E; i += st) {
        int p = atomicAdd(&cur[dst[i]], 1);
        esrc[p] = src[i];
    }
}

__global__ void k_dinv(const int* __restrict__ row_off, float* __restrict__ dinv, int N) {
    int i = blockIdx.x * blockDim.x + threadIdx.x;
    if (i < N) dinv[i] = rsqrtf((float)(row_off[i + 1] - row_off[i] + 1));
}

// ---------------------------------------------------------------------------
// Register-tiled f32 GEMM: G[n][0..OF) = (X[row(n)] @ W) * dinv[n], G stride 64.
// BM=128, BK=32, thread tile 8x4. NT = 16*(OF/4) threads.
// ---------------------------------------------------------------------------
template <int K, int OF, int NT>
__global__ __launch_bounds__(NT) void k_gemm_t(
    const float* __restrict__ X, int sx,
    const int* __restrict__ nodes,      // may be null (identity)
    const float* __restrict__ W,        // [K][OF] row-major
    const float* __restrict__ dinv,
    float* __restrict__ G,              // stride 64
    int N)
{
    constexpr int BM = 128, BK = 32, TM = 8, TN = 4;
    constexpr int NCG = OF / TN;        // col groups
    constexpr int LDA = BM + 4;         // keeps 16B alignment, spreads banks
    static_assert(NT == 16 * NCG, "thread count mismatch");

    __shared__ float As[BK * LDA];      // k-major: As[k][m]
    __shared__ float Bs[BK * OF];       // Bs[k][n]

    const int tid = threadIdx.x;
    const int cg = tid % NCG;
    const int rg = tid / NCG;           // 0..15
    const int m0 = blockIdx.x * BM;

    float acc[TM][TN];
#pragma unroll
    for (int i = 0; i < TM; i++)
#pragma unroll
        for (int j = 0; j < TN; j++) acc[i][j] = 0.f;

    for (int k0 = 0; k0 < K; k0 += BK) {
        __syncthreads();
        // stage A (transpose to k-major)
        for (int i = tid; i < BM * BK / 4; i += NT) {
            int m = i / (BK / 4);
            int kq = i % (BK / 4);
            float4 v = make_float4(0.f, 0.f, 0.f, 0.f);
            if (m0 + m < N) {
                long row = nodes ? (long)nodes[m0 + m] : (long)(m0 + m);
                v = *reinterpret_cast<const float4*>(X + row * (long)sx + k0 + kq * 4);
            }
            float* a = &As[(kq * 4) * LDA + m];
            a[0 * LDA] = v.x; a[1 * LDA] = v.y; a[2 * LDA] = v.z; a[3 * LDA] = v.w;
        }
        // stage B
        for (int i = tid; i < BK * OF / 4; i += NT) {
            int k = i / (OF / 4);
            int nq = i % (OF / 4);
            *reinterpret_cast<float4*>(&Bs[k * OF + nq * 4]) =
                *reinterpret_cast<const float4*>(W + (long)(k0 + k) * OF + nq * 4);
        }
        __syncthreads();
#pragma unroll
        for (int kk = 0; kk < BK; ++kk) {
            float4 a0 = *reinterpret_cast<const float4*>(&As[kk * LDA + rg * TM]);
            float4 a1 = *reinterpret_cast<const float4*>(&As[kk * LDA + rg * TM + 4]);
            float4 bv = *reinterpret_cast<const float4*>(&Bs[kk * OF + cg * TN]);
            float av[TM] = {a0.x, a0.y, a0.z, a0.w, a1.x, a1.y, a1.z, a1.w};
            float bw[TN] = {bv.x, bv.y, bv.z, bv.w};
#pragma unroll
            for (int i = 0; i < TM; i++)
#pragma unroll
                for (int j = 0; j < TN; j++)
                    acc[i][j] = fmaf(av[i], bw[j], acc[i][j]);
        }
    }
    // epilogue: scale by dinv, store
#pragma unroll
    for (int i = 0; i < TM; i++) {
        int m = m0 + rg * TM + i;
        if (m < N) {
            float dv = dinv[m];
            float4 o;
            o.x = acc[i][0] * dv; o.y = acc[i][1] * dv;
            o.z = acc[i][2] * dv; o.w = acc[i][3] * dv;
            *reinterpret_cast<float4*>(&G[(long)m * 64 + cg * TN]) = o;
        }
    }
}

// ---------------------------------------------------------------------------
// CSR aggregation + self-loop + epilogue. One wave per node.
// F lanes per feature slice, 64/F edges processed in parallel.
// ---------------------------------------------------------------------------
template <int F, int OSTRIDE>
__global__ __launch_bounds__(256) void k_agg(
    const int* __restrict__ row_off, const int* __restrict__ esrc,
    const float* __restrict__ g,     // stride 64
    const float* __restrict__ dinv, const float* __restrict__ b,
    float* __restrict__ y, int N)
{
    constexpr int EPW = 64 / F;
    const int lane = threadIdx.x & 63;
    const int f = lane % F;
    const int sub = lane / F;
    const int wid = blockIdx.x * (blockDim.x >> 6) + (threadIdx.x >> 6);
    if (wid >= N) return;
    const int n = wid;
    const int start = row_off[n], end = row_off[n + 1];

    float a0 = 0.f, a1 = 0.f, a2 = 0.f, a3 = 0.f;
    int e = start + sub;
    for (; e + 3 * EPW < end; e += 4 * EPW) {
        int s0 = esrc[e];
        int s1 = esrc[e + EPW];
        int s2 = esrc[e + 2 * EPW];
        int s3 = esrc[e + 3 * EPW];
        a0 += g[(long)s0 * 64 + f];
        a1 += g[(long)s1 * 64 + f];
        a2 += g[(long)s2 * 64 + f];
        a3 += g[(long)s3 * 64 + f];
    }
    for (; e < end; e += EPW) a0 += g[(long)esrc[e] * 64 + f];
    float acc = (a0 + a1) + (a2 + a3);
#pragma unroll
    for (int m = F; m < 64; m <<= 1) acc += __shfl_xor(acc, m, 64);
    if (sub == 0) {
        float t = acc + g[(long)n * 64 + f];          // self loop
        float v = fmaf(t, dinv[n], b[f]);
        y[(long)n * OSTRIDE + f] = fmaxf(v, 0.f);
    }
}

extern "C" void kernel_launch(void* const* d_in, const int* in_sizes, int n_in,
                              void* d_out, int out_size, void* d_ws, size_t ws_size,
                              hipStream_t stream) {
    const int*   nodes = (const int*)d_in[0];
    const int*   edges = (const int*)d_in[1];
    const float* emb   = (const float*)d_in[2];
    const float* W1    = (const float*)d_in[3];
    const float* b1    = (const float*)d_in[4];
    const float* W2    = (const float*)d_in[5];
    const float* b2    = (const float*)d_in[6];
    const float* W3    = (const float*)d_in[7];
    const float* b3    = (const float*)d_in[8];

    const int N = in_sizes[0];
    const int E = in_sizes[1] / 2;
    const int* src  = edges;
    const int* dstv = edges + E;

    // workspace layout (256B-aligned slices)
    char* ws = (char*)d_ws;
    size_t off = 0;
    auto alloc = [&](size_t bytes) {
        char* p = ws + off;
        off += (bytes + 255) & ~(size_t)255;
        return p;
    };
    float* dinv    = (float*)alloc((size_t)N * 4);
    int*   row_off = (int*)  alloc((size_t)(N + 1) * 4);
    int*   bsum    = (int*)  alloc(1024 * 4);
    int*   counts  = (int*)  alloc((size_t)N * 4);      // reused as cursor
    int*   esrc    = (int*)  alloc((size_t)E * 4);
    float* G       = (float*)alloc((size_t)N * 64 * 4);
    float* Xb      = (float*)alloc((size_t)N * 64 * 4);
    float* out     = (float*)d_out;

    const int nbN = (N + 255) / 256;
    const int nb1 = nbN;  // scanA blocks

    // --- CSR build + dinv (shared by all 3 layers) ---
    hipLaunchKernelGGL(k_zero_i,  dim3(nbN),  dim3(256), 0, stream, counts, N);
    hipLaunchKernelGGL(k_hist,    dim3(4096), dim3(256), 0, stream, dstv, counts, E);
    hipLaunchKernelGGL(k_scanA,   dim3(nb1),  dim3(256), 0, stream, counts, row_off + 1, bsum, N);
    hipLaunchKernelGGL(k_scanB,   dim3(1),    dim3(1024), 0, stream, bsum, nb1);
    hipLaunchKernelGGL(k_scanC,   dim3(nb1),  dim3(256), 0, stream, row_off, bsum, counts, N);
    hipLaunchKernelGGL(k_scatter, dim3(4096), dim3(256), 0, stream, src, dstv, counts, esrc, E);
    hipLaunchKernelGGL(k_dinv,    dim3(nbN),  dim3(256), 0, stream, row_off, dinv, N);

    const int gemm_blocks = (N + 127) / 128;
    const int agg_blocks  = (N + 3) / 4;   // 4 waves / block

    // --- layer 1: 256 -> 64 ---
    hipLaunchKernelGGL((k_gemm_t<256, 64, 256>), dim3(gemm_blocks), dim3(256), 0, stream,
                       emb, 256, nodes, W1, dinv, G, N);
    hipLaunchKernelGGL((k_agg<64, 64>), dim3(agg_blocks), dim3(256), 0, stream,
                       row_off, esrc, G, dinv, b1, Xb, N);
    // --- layer 2: 64 -> 32 ---
    hipLaunchKernelGGL((k_gemm_t<64, 32, 128>), dim3(gemm_blocks), dim3(128), 0, stream,
                       Xb, 64, (const int*)nullptr, W2, dinv, G, N);
    hipLaunchKernelGGL((k_agg<32, 64>), dim3(agg_blocks), dim3(256), 0, stream,
                       row_off, esrc, G, dinv, b2, Xb, N);
    // --- layer 3: 32 -> 16 ---
    hipLaunchKernelGGL((k_gemm_t<32, 16, 64>), dim3(gemm_blocks), dim3(64), 0, stream,
                       Xb, 64, (const int*)nullptr, W3, dinv, G, N);
    hipLaunchKernelGGL((k_agg<16, 16>), dim3(agg_blocks), dim3(256), 0, stream,
                       row_off, esrc, G, dinv, b3, out, N);
}

// Round 3
// 446.570 us; speedup vs baseline: 4.4480x; 1.6994x over previous
//
#include <hip/hip_runtime.h>

// ---------------------------------------------------------------------------
// 3-layer GCN forward. out[d] = relu( dinv[d]*( sum_{s->d} g[s] + g[d] ) + b ),
// g = (x@W)*dinv.
// CSR built per call via two-level counting sort (bucket = dst>>9):
//   k_bhist -> k_bscan -> k_part (bucket-contiguous pairs) -> k_bucket
//   (per-bucket LDS histogram/scan/scatter; also emits row_off + dinv).
// All scatter targets stay L2-resident => no partial-line write amplification.
// ---------------------------------------------------------------------------

#define BSH 9                 // 512 nodes per bucket
#define BNODES (1 << BSH)

__global__ void k_zero_i(int* __restrict__ p, int n) {
    int i = blockIdx.x * blockDim.x + threadIdx.x;
    if (i < n) p[i] = 0;
}

// bucket histogram of dst
__global__ __launch_bounds__(256) void k_bhist(const int* __restrict__ dst,
                                               int* __restrict__ bcnt, int E) {
    __shared__ int h[256];
    int t = threadIdx.x;
    h[t] = 0;
    __syncthreads();
    for (int i = blockIdx.x * 256 + t; i < E; i += gridDim.x * 256)
        atomicAdd(&h[dst[i] >> BSH], 1);
    __syncthreads();
    if (h[t]) atomicAdd(&bcnt[t], h[t]);
}

// scan bucket counts -> boff[NB+1] (exclusive), init bcur. NB <= 1024.
__global__ __launch_bounds__(1024) void k_bscan(const int* __restrict__ bcnt,
                                                int* __restrict__ boff,
                                                int* __restrict__ bcur, int NB) {
    __shared__ int s[1024];
    int t = threadIdx.x;
    int v = (t < NB) ? bcnt[t] : 0;
    s[t] = v;
    __syncthreads();
    for (int off = 1; off < 1024; off <<= 1) {
        int a = (t >= off) ? s[t - off] : 0;
        __syncthreads();
        s[t] += a;
        __syncthreads();
    }
    if (t < NB) {
        int ex = s[t] - v;
        boff[t] = ex;
        bcur[t] = ex;
    }
    if (t == NB - 1) boff[NB] = s[t];
}

// partition edges into bucket-contiguous (src,dst) pairs
template <int CH>
__global__ __launch_bounds__(256) void k_part(const int* __restrict__ src,
                                              const int* __restrict__ dst,
                                              int* __restrict__ bcur,
                                              int2* __restrict__ pairs,
                                              int E, int NB) {
    __shared__ int lh[256];
    __shared__ int lbase[256];
    const int t = threadIdx.x;
    const int e0 = blockIdx.x * CH;
    const int n = min(CH, E - e0);

    lh[t] = 0;
    __syncthreads();
    for (int i = t; i < n; i += 256) atomicAdd(&lh[dst[e0 + i] >> BSH], 1);
    __syncthreads();
    if (t < NB && lh[t] > 0) lbase[t] = atomicAdd(&bcur[t], lh[t]);
    __syncthreads();
    lh[t] = 0;
    __syncthreads();
    for (int i = t; i < n; i += 256) {
        int d = dst[e0 + i];
        int b = d >> BSH;
        int r = atomicAdd(&lh[b], 1);
        pairs[(long)lbase[b] + r] = make_int2(src[e0 + i], d);
    }
}

// per-bucket: per-node histogram + scan (LDS), emit row_off/dinv, scatter esrc
__global__ __launch_bounds__(1024) void k_bucket(const int2* __restrict__ pairs,
                                                 const int* __restrict__ boff,
                                                 int* __restrict__ row_off,
                                                 float* __restrict__ dinv,
                                                 int* __restrict__ esrc,
                                                 int N, int NB, int E) {
    __shared__ int cnt[BNODES];
    __shared__ int sc[BNODES];
    __shared__ int cur[BNODES];
    const int b = blockIdx.x;
    const int t = threadIdx.x;
    const int base = b << BSH;
    const int nn = min(BNODES, N - base);
    const int ebase = boff[b], eend = boff[b + 1];

    if (t < BNODES) cnt[t] = 0;
    __syncthreads();
    for (int e = ebase + t; e < eend; e += 1024)
        atomicAdd(&cnt[pairs[e].y - base], 1);
    __syncthreads();
    if (t < BNODES) sc[t] = cnt[t];
    __syncthreads();
    for (int off = 1; off < BNODES; off <<= 1) {
        int a = (t < BNODES && t >= off) ? sc[t - off] : 0;
        __syncthreads();
        if (t < BNODES) sc[t] += a;
        __syncthreads();
    }
    if (t < nn) {
        int ex = sc[t] - cnt[t];
        row_off[base + t] = ebase + ex;
        cur[t] = ex;
        dinv[base + t] = rsqrtf((float)(cnt[t] + 1));
    }
    if (b == NB - 1 && t == 0) row_off[N] = E;
    __syncthreads();
    for (int e = ebase + t; e < eend; e += 1024) {
        int2 p = pairs[e];
        int r = atomicAdd(&cur[p.y - base], 1);
        esrc[ebase + r] = p.x;
    }
}

// ---------------------------------------------------------------------------
// Register-tiled f32 GEMM: G[n][0..OF) = (X[row(n)] @ W) * dinv[n], G stride 64.
// BM=128, BK=32, thread tile 8x4. NT = 16*(OF/4) threads.
// ---------------------------------------------------------------------------
template <int K, int OF, int NT>
__global__ __launch_bounds__(NT) void k_gemm_t(
    const float* __restrict__ X, int sx,
    const int* __restrict__ nodes,      // may be null (identity)
    const float* __restrict__ W,        // [K][OF] row-major
    const float* __restrict__ dinv,
    float* __restrict__ G,              // stride 64
    int N)
{
    constexpr int BM = 128, BK = 32, TM = 8, TN = 4;
    constexpr int NCG = OF / TN;        // col groups
    constexpr int LDA = BM + 4;
    static_assert(NT == 16 * NCG, "thread count mismatch");

    __shared__ float As[BK * LDA];      // k-major: As[k][m]
    __shared__ float Bs[BK * OF];       // Bs[k][n]

    const int tid = threadIdx.x;
    const int cg = tid % NCG;
    const int rg = tid / NCG;           // 0..15
    const int m0 = blockIdx.x * BM;

    float acc[TM][TN];
#pragma unroll
    for (int i = 0; i < TM; i++)
#pragma unroll
        for (int j = 0; j < TN; j++) acc[i][j] = 0.f;

    for (int k0 = 0; k0 < K; k0 += BK) {
        __syncthreads();
        for (int i = tid; i < BM * BK / 4; i += NT) {
            int m = i / (BK / 4);
            int kq = i % (BK / 4);
            float4 v = make_float4(0.f, 0.f, 0.f, 0.f);
            if (m0 + m < N) {
                long row = nodes ? (long)nodes[m0 + m] : (long)(m0 + m);
                v = *reinterpret_cast<const float4*>(X + row * (long)sx + k0 + kq * 4);
            }
            float* a = &As[(kq * 4) * LDA + m];
            a[0 * LDA] = v.x; a[1 * LDA] = v.y; a[2 * LDA] = v.z; a[3 * LDA] = v.w;
        }
        for (int i = tid; i < BK * OF / 4; i += NT) {
            int k = i / (OF / 4);
            int nq = i % (OF / 4);
            *reinterpret_cast<float4*>(&Bs[k * OF + nq * 4]) =
                *reinterpret_cast<const float4*>(W + (long)(k0 + k) * OF + nq * 4);
        }
        __syncthreads();
#pragma unroll
        for (int kk = 0; kk < BK; ++kk) {
            float4 a0 = *reinterpret_cast<const float4*>(&As[kk * LDA + rg * TM]);
            float4 a1 = *reinterpret_cast<const float4*>(&As[kk * LDA + rg * TM + 4]);
            float4 bv = *reinterpret_cast<const float4*>(&Bs[kk * OF + cg * TN]);
            float av[TM] = {a0.x, a0.y, a0.z, a0.w, a1.x, a1.y, a1.z, a1.w};
            float bw[TN] = {bv.x, bv.y, bv.z, bv.w};
#pragma unroll
            for (int i = 0; i < TM; i++)
#pragma unroll
                for (int j = 0; j < TN; j++)
                    acc[i][j] = fmaf(av[i], bw[j], acc[i][j]);
        }
    }
#pragma unroll
    for (int i = 0; i < TM; i++) {
        int m = m0 + rg * TM + i;
        if (m < N) {
            float dv = dinv[m];
            float4 o;
            o.x = acc[i][0] * dv; o.y = acc[i][1] * dv;
            o.z = acc[i][2] * dv; o.w = acc[i][3] * dv;
            *reinterpret_cast<float4*>(&G[(long)m * 64 + cg * TN]) = o;
        }
    }
}

// ---------------------------------------------------------------------------
// CSR aggregation + self-loop + epilogue. One wave per node.
// ---------------------------------------------------------------------------
template <int F, int OSTRIDE>
__global__ __launch_bounds__(256) void k_agg(
    const int* __restrict__ row_off, const int* __restrict__ esrc,
    const float* __restrict__ g,     // stride 64
    const float* __restrict__ dinv, const float* __restrict__ b,
    float* __restrict__ y, int N)
{
    constexpr int EPW = 64 / F;
    const int lane = threadIdx.x & 63;
    const int f = lane % F;
    const int sub = lane / F;
    const int wid = blockIdx.x * (blockDim.x >> 6) + (threadIdx.x >> 6);
    if (wid >= N) return;
    const int n = wid;
    const int start = row_off[n], end = row_off[n + 1];

    float a0 = 0.f, a1 = 0.f, a2 = 0.f, a3 = 0.f;
    int e = start + sub;
    for (; e + 3 * EPW < end; e += 4 * EPW) {
        int s0 = esrc[e];
        int s1 = esrc[e + EPW];
        int s2 = esrc[e + 2 * EPW];
        int s3 = esrc[e + 3 * EPW];
        a0 += g[(long)s0 * 64 + f];
        a1 += g[(long)s1 * 64 + f];
        a2 += g[(long)s2 * 64 + f];
        a3 += g[(long)s3 * 64 + f];
    }
    for (; e < end; e += EPW) a0 += g[(long)esrc[e] * 64 + f];
    float acc = (a0 + a1) + (a2 + a3);
#pragma unroll
    for (int m = F; m < 64; m <<= 1) acc += __shfl_xor(acc, m, 64);
    if (sub == 0) {
        float t = acc + g[(long)n * 64 + f];          // self loop
        float v = fmaf(t, dinv[n], b[f]);
        y[(long)n * OSTRIDE + f] = fmaxf(v, 0.f);
    }
}

extern "C" void kernel_launch(void* const* d_in, const int* in_sizes, int n_in,
                              void* d_out, int out_size, void* d_ws, size_t ws_size,
                              hipStream_t stream) {
    const int*   nodes = (const int*)d_in[0];
    const int*   edges = (const int*)d_in[1];
    const float* emb   = (const float*)d_in[2];
    const float* W1    = (const float*)d_in[3];
    const float* b1    = (const float*)d_in[4];
    const float* W2    = (const float*)d_in[5];
    const float* b2    = (const float*)d_in[6];
    const float* W3    = (const float*)d_in[7];
    const float* b3    = (const float*)d_in[8];

    const int N = in_sizes[0];
    const int E = in_sizes[1] / 2;
    const int* src  = edges;
    const int* dstv = edges + E;
    const int NB = (N + BNODES - 1) >> BSH;   // 196 for N=100000

    // workspace layout (256B-aligned slices)
    char* ws = (char*)d_ws;
    size_t off = 0;
    auto alloc = [&](size_t bytes) {
        char* p = ws + off;
        off += (bytes + 255) & ~(size_t)255;
        return p;
    };
    float* dinv    = (float*)alloc((size_t)N * 4);
    int*   row_off = (int*)  alloc((size_t)(N + 1) * 4);
    int*   bcnt    = (int*)  alloc((size_t)(NB + 1) * 4);
    int*   boff    = (int*)  alloc((size_t)(NB + 1) * 4);
    int*   bcur    = (int*)  alloc((size_t)NB * 4);
    int*   esrc    = (int*)  alloc((size_t)E * 4);
    char*  shared_region = alloc((size_t)E * 8);        // pairs (25.6MB) ...
    int2*  pairs   = (int2*)shared_region;
    float* G       = (float*)shared_region;             // ... aliases G (25.6MB)
    float* Xb      = (float*)alloc((size_t)N * 64 * 4);
    float* out     = (float*)d_out;

    // --- CSR build + dinv (shared by all 3 layers) ---
    constexpr int CH = 8192;
    const int nch = (E + CH - 1) / CH;
    hipLaunchKernelGGL(k_zero_i, dim3((NB + 255) / 256), dim3(256), 0, stream, bcnt, NB);
    hipLaunchKernelGGL(k_bhist,  dim3(1024), dim3(256), 0, stream, dstv, bcnt, E);
    hipLaunchKernelGGL(k_bscan,  dim3(1), dim3(1024), 0, stream, bcnt, boff, bcur, NB);
    hipLaunchKernelGGL((k_part<CH>), dim3(nch), dim3(256), 0, stream,
                       src, dstv, bcur, pairs, E, NB);
    hipLaunchKernelGGL(k_bucket, dim3(NB), dim3(1024), 0, stream,
                       pairs, boff, row_off, dinv, esrc, N, NB, E);

    const int gemm_blocks = (N + 127) / 128;
    const int agg_blocks  = (N + 3) / 4;   // 4 waves / block

    // --- layer 1: 256 -> 64 ---  (G overwrites pairs; pairs dead after k_bucket)
    hipLaunchKernelGGL((k_gemm_t<256, 64, 256>), dim3(gemm_blocks), dim3(256), 0, stream,
                       emb, 256, nodes, W1, dinv, G, N);
    hipLaunchKernelGGL((k_agg<64, 64>), dim3(agg_blocks), dim3(256), 0, stream,
                       row_off, esrc, G, dinv, b1, Xb, N);
    // --- layer 2: 64 -> 32 ---
    hipLaunchKernelGGL((k_gemm_t<64, 32, 128>), dim3(gemm_blocks), dim3(128), 0, stream,
                       Xb, 64, (const int*)nullptr, W2, dinv, G, N);
    hipLaunchKernelGGL((k_agg<32, 64>), dim3(agg_blocks), dim3(256), 0, stream,
                       row_off, esrc, G, dinv, b2, Xb, N);
    // --- layer 3: 32 -> 16 ---
    hipLaunchKernelGGL((k_gemm_t<32, 16, 64>), dim3(gemm_blocks), dim3(64), 0, stream,
                       Xb, 64, (const int*)nullptr, W3, dinv, G, N);
    hipLaunchKernelGGL((k_agg<16, 16>), dim3(agg_blocks), dim3(256), 0, stream,
                       row_off, esrc, G, dinv, b3, out, N);
}

// Round 4
// 386.254 us; speedup vs baseline: 5.1426x; 1.1562x over previous
//
#include <hip/hip_runtime.h>

// ---------------------------------------------------------------------------
// 3-layer GCN forward. out[d] = relu( dinv[d]*( sum_{s->d} g[s] + g[d] ) + b ),
// g = (x@W)*dinv  -- stored in bf16 (halves random-gather traffic; accumulate
// in f32). CSR built per call via two-level counting sort (bucket = dst>>9).
// ---------------------------------------------------------------------------

#define BSH 9                 // 512 nodes per bucket
#define BNODES (1 << BSH)

__device__ inline ushort f2bf(float x) {   // round-to-nearest-even f32->bf16
    uint u = __float_as_uint(x);
    return (ushort)((u + 0x7fffu + ((u >> 16) & 1u)) >> 16);
}

__global__ void k_zero_i(int* __restrict__ p, int n) {
    int i = blockIdx.x * blockDim.x + threadIdx.x;
    if (i < n) p[i] = 0;
}

// bucket histogram of dst
__global__ __launch_bounds__(256) void k_bhist(const int* __restrict__ dst,
                                               int* __restrict__ bcnt, int E) {
    __shared__ int h[256];
    int t = threadIdx.x;
    h[t] = 0;
    __syncthreads();
    for (int i = blockIdx.x * 256 + t; i < E; i += gridDim.x * 256)
        atomicAdd(&h[dst[i] >> BSH], 1);
    __syncthreads();
    if (h[t]) atomicAdd(&bcnt[t], h[t]);
}

// scan bucket counts -> boff[NB+1] (exclusive), init bcur. NB <= 1024.
__global__ __launch_bounds__(1024) void k_bscan(const int* __restrict__ bcnt,
                                                int* __restrict__ boff,
                                                int* __restrict__ bcur, int NB) {
    __shared__ int s[1024];
    int t = threadIdx.x;
    int v = (t < NB) ? bcnt[t] : 0;
    s[t] = v;
    __syncthreads();
    for (int off = 1; off < 1024; off <<= 1) {
        int a = (t >= off) ? s[t - off] : 0;
        __syncthreads();
        s[t] += a;
        __syncthreads();
    }
    if (t < NB) {
        int ex = s[t] - v;
        boff[t] = ex;
        bcur[t] = ex;
    }
    if (t == NB - 1) boff[NB] = s[t];
}

// partition edges into bucket-contiguous (src,dst) pairs
template <int CH>
__global__ __launch_bounds__(256) void k_part(const int* __restrict__ src,
                                              const int* __restrict__ dst,
                                              int* __restrict__ bcur,
                                              int2* __restrict__ pairs,
                                              int E, int NB) {
    __shared__ int lh[256];
    __shared__ int lbase[256];
    const int t = threadIdx.x;
    const int e0 = blockIdx.x * CH;
    const int n = min(CH, E - e0);

    lh[t] = 0;
    __syncthreads();
    for (int i = t; i < n; i += 256) atomicAdd(&lh[dst[e0 + i] >> BSH], 1);
    __syncthreads();
    if (t < NB && lh[t] > 0) lbase[t] = atomicAdd(&bcur[t], lh[t]);
    __syncthreads();
    lh[t] = 0;
    __syncthreads();
    for (int i = t; i < n; i += 256) {
        int d = dst[e0 + i];
        int b = d >> BSH;
        int r = atomicAdd(&lh[b], 1);
        pairs[(long)lbase[b] + r] = make_int2(src[e0 + i], d);
    }
}

// per-bucket: per-node histogram + scan (LDS), emit row_off/dinv, scatter esrc
__global__ __launch_bounds__(1024) void k_bucket(const int2* __restrict__ pairs,
                                                 const int* __restrict__ boff,
                                                 int* __restrict__ row_off,
                                                 float* __restrict__ dinv,
                                                 int* __restrict__ esrc,
                                                 int N, int NB, int E) {
    __shared__ int cnt[BNODES];
    __shared__ int sc[BNODES];
    __shared__ int cur[BNODES];
    const int b = blockIdx.x;
    const int t = threadIdx.x;
    const int base = b << BSH;
    const int nn = min(BNODES, N - base);
    const int ebase = boff[b], eend = boff[b + 1];

    if (t < BNODES) cnt[t] = 0;
    __syncthreads();
    for (int e = ebase + t; e < eend; e += 1024)
        atomicAdd(&cnt[pairs[e].y - base], 1);
    __syncthreads();
    if (t < BNODES) sc[t] = cnt[t];
    __syncthreads();
    for (int off = 1; off < BNODES; off <<= 1) {
        int a = (t < BNODES && t >= off) ? sc[t - off] : 0;
        __syncthreads();
        if (t < BNODES) sc[t] += a;
        __syncthreads();
    }
    if (t < nn) {
        int ex = sc[t] - cnt[t];
        row_off[base + t] = ebase + ex;
        cur[t] = ex;
        dinv[base + t] = rsqrtf((float)(cnt[t] + 1));
    }
    if (b == NB - 1 && t == 0) row_off[N] = E;
    __syncthreads();
    for (int e = ebase + t; e < eend; e += 1024) {
        int2 p = pairs[e];
        int r = atomicAdd(&cur[p.y - base], 1);
        esrc[ebase + r] = p.x;
    }
}

// ---------------------------------------------------------------------------
// Register-tiled f32 GEMM -> bf16 output:
// G[n][0..OF) = bf16( (X[row(n)] @ W) * dinv[n] ), packed rows (stride OF).
// BM=128, BK=32, thread tile 8x4. NT = 16*(OF/4) threads.
// ---------------------------------------------------------------------------
template <int K, int OF, int NT>
__global__ __launch_bounds__(NT) void k_gemm_t(
    const float* __restrict__ X, int sx,
    const int* __restrict__ nodes,      // may be null (identity)
    const float* __restrict__ W,        // [K][OF] row-major
    const float* __restrict__ dinv,
    ushort* __restrict__ G,             // bf16, packed stride OF
    int N)
{
    constexpr int BM = 128, BK = 32, TM = 8, TN = 4;
    constexpr int NCG = OF / TN;
    constexpr int LDA = BM + 4;
    static_assert(NT == 16 * NCG, "thread count mismatch");

    __shared__ float As[BK * LDA];      // k-major: As[k][m]
    __shared__ float Bs[BK * OF];       // Bs[k][n]

    const int tid = threadIdx.x;
    const int cg = tid % NCG;
    const int rg = tid / NCG;           // 0..15
    const int m0 = blockIdx.x * BM;

    float acc[TM][TN];
#pragma unroll
    for (int i = 0; i < TM; i++)
#pragma unroll
        for (int j = 0; j < TN; j++) acc[i][j] = 0.f;

    for (int k0 = 0; k0 < K; k0 += BK) {
        __syncthreads();
        for (int i = tid; i < BM * BK / 4; i += NT) {
            int m = i / (BK / 4);
            int kq = i % (BK / 4);
            float4 v = make_float4(0.f, 0.f, 0.f, 0.f);
            if (m0 + m < N) {
                long row = nodes ? (long)nodes[m0 + m] : (long)(m0 + m);
                v = *reinterpret_cast<const float4*>(X + row * (long)sx + k0 + kq * 4);
            }
            float* a = &As[(kq * 4) * LDA + m];
            a[0 * LDA] = v.x; a[1 * LDA] = v.y; a[2 * LDA] = v.z; a[3 * LDA] = v.w;
        }
        for (int i = tid; i < BK * OF / 4; i += NT) {
            int k = i / (OF / 4);
            int nq = i % (OF / 4);
            *reinterpret_cast<float4*>(&Bs[k * OF + nq * 4]) =
                *reinterpret_cast<const float4*>(W + (long)(k0 + k) * OF + nq * 4);
        }
        __syncthreads();
#pragma unroll
        for (int kk = 0; kk < BK; ++kk) {
            float4 a0 = *reinterpret_cast<const float4*>(&As[kk * LDA + rg * TM]);
            float4 a1 = *reinterpret_cast<const float4*>(&As[kk * LDA + rg * TM + 4]);
            float4 bv = *reinterpret_cast<const float4*>(&Bs[kk * OF + cg * TN]);
            float av[TM] = {a0.x, a0.y, a0.z, a0.w, a1.x, a1.y, a1.z, a1.w};
            float bw[TN] = {bv.x, bv.y, bv.z, bv.w};
#pragma unroll
            for (int i = 0; i < TM; i++)
#pragma unroll
                for (int j = 0; j < TN; j++)
                    acc[i][j] = fmaf(av[i], bw[j], acc[i][j]);
        }
    }
#pragma unroll
    for (int i = 0; i < TM; i++) {
        int m = m0 + rg * TM + i;
        if (m < N) {
            float dv = dinv[m];
            ushort4 o;
            o.x = f2bf(acc[i][0] * dv);
            o.y = f2bf(acc[i][1] * dv);
            o.z = f2bf(acc[i][2] * dv);
            o.w = f2bf(acc[i][3] * dv);
            *reinterpret_cast<ushort4*>(&G[(long)m * OF + cg * TN]) = o;
        }
    }
}

// ---------------------------------------------------------------------------
// CSR aggregation (bf16 gather, f32 accum) + self-loop + epilogue.
// One wave per node; OF/2 lanes per edge (each lane one bf16x2 word).
// ---------------------------------------------------------------------------
template <int OF, int OSTRIDE>
__global__ __launch_bounds__(256) void k_agg(
    const int* __restrict__ row_off, const int* __restrict__ esrc,
    const uint* __restrict__ g,      // bf16x2 words, row = OF/2 words
    const float* __restrict__ dinv, const float* __restrict__ b,
    float* __restrict__ y, int N)
{
    constexpr int F2 = OF / 2;       // lanes (words) per edge
    constexpr int EPW = 64 / F2;     // edges per wave per step
    const int lane = threadIdx.x & 63;
    const int f2 = lane % F2;
    const int sub = lane / F2;
    const int wid = blockIdx.x * (blockDim.x >> 6) + (threadIdx.x >> 6);
    if (wid >= N) return;
    const int n = wid;
    const int start = row_off[n], end = row_off[n + 1];

    float ax0 = 0.f, ay0 = 0.f, ax1 = 0.f, ay1 = 0.f;
    float ax2 = 0.f, ay2 = 0.f, ax3 = 0.f, ay3 = 0.f;
    int e = start + sub;
    for (; e + 3 * EPW < end; e += 4 * EPW) {
        uint w0 = g[(long)esrc[e]           * F2 + f2];
        uint w1 = g[(long)esrc[e + EPW]     * F2 + f2];
        uint w2 = g[(long)esrc[e + 2 * EPW] * F2 + f2];
        uint w3 = g[(long)esrc[e + 3 * EPW] * F2 + f2];
        ax0 += __uint_as_float(w0 << 16); ay0 += __uint_as_float(w0 & 0xffff0000u);
        ax1 += __uint_as_float(w1 << 16); ay1 += __uint_as_float(w1 & 0xffff0000u);
        ax2 += __uint_as_float(w2 << 16); ay2 += __uint_as_float(w2 & 0xffff0000u);
        ax3 += __uint_as_float(w3 << 16); ay3 += __uint_as_float(w3 & 0xffff0000u);
    }
    for (; e < end; e += EPW) {
        uint w = g[(long)esrc[e] * F2 + f2];
        ax0 += __uint_as_float(w << 16);
        ay0 += __uint_as_float(w & 0xffff0000u);
    }
    float accx = (ax0 + ax1) + (ax2 + ax3);
    float accy = (ay0 + ay1) + (ay2 + ay3);
#pragma unroll
    for (int m = F2; m < 64; m <<= 1) {
        accx += __shfl_xor(accx, m, 64);
        accy += __shfl_xor(accy, m, 64);
    }
    if (sub == 0) {
        uint sv = g[(long)n * F2 + f2];   // self loop
        float tx = accx + __uint_as_float(sv << 16);
        float ty = accy + __uint_as_float(sv & 0xffff0000u);
        float dv = dinv[n];
        float2 o;
        o.x = fmaxf(fmaf(tx, dv, b[2 * f2]), 0.f);
        o.y = fmaxf(fmaf(ty, dv, b[2 * f2 + 1]), 0.f);
        *reinterpret_cast<float2*>(&y[(long)n * OSTRIDE + 2 * f2]) = o;
    }
}

extern "C" void kernel_launch(void* const* d_in, const int* in_sizes, int n_in,
                              void* d_out, int out_size, void* d_ws, size_t ws_size,
                              hipStream_t stream) {
    const int*   nodes = (const int*)d_in[0];
    const int*   edges = (const int*)d_in[1];
    const float* emb   = (const float*)d_in[2];
    const float* W1    = (const float*)d_in[3];
    const float* b1    = (const float*)d_in[4];
    const float* W2    = (const float*)d_in[5];
    const float* b2    = (const float*)d_in[6];
    const float* W3    = (const float*)d_in[7];
    const float* b3    = (const float*)d_in[8];

    const int N = in_sizes[0];
    const int E = in_sizes[1] / 2;
    const int* src  = edges;
    const int* dstv = edges + E;
    const int NB = (N + BNODES - 1) >> BSH;   // 196 for N=100000

    // workspace layout (256B-aligned slices)
    char* ws = (char*)d_ws;
    size_t off = 0;
    auto alloc = [&](size_t bytes) {
        char* p = ws + off;
        off += (bytes + 255) & ~(size_t)255;
        return p;
    };
    float* dinv    = (float*)alloc((size_t)N * 4);
    int*   row_off = (int*)  alloc((size_t)(N + 1) * 4);
    int*   bcnt    = (int*)  alloc((size_t)(NB + 1) * 4);
    int*   boff    = (int*)  alloc((size_t)(NB + 1) * 4);
    int*   bcur    = (int*)  alloc((size_t)NB * 4);
    int*   esrc    = (int*)  alloc((size_t)E * 4);
    char*  shared_region = alloc((size_t)E * 8);        // pairs (25.6MB) ...
    int2*  pairs   = (int2*)shared_region;
    ushort* G      = (ushort*)shared_region;            // ... aliases G bf16 (<=12.8MB)
    float* Xb      = (float*)alloc((size_t)N * 64 * 4);
    float* out     = (float*)d_out;

    // --- CSR build + dinv (shared by all 3 layers) ---
    constexpr int CH = 8192;
    const int nch = (E + CH - 1) / CH;
    hipLaunchKernelGGL(k_zero_i, dim3((NB + 255) / 256), dim3(256), 0, stream, bcnt, NB);
    hipLaunchKernelGGL(k_bhist,  dim3(1024), dim3(256), 0, stream, dstv, bcnt, E);
    hipLaunchKernelGGL(k_bscan,  dim3(1), dim3(1024), 0, stream, bcnt, boff, bcur, NB);
    hipLaunchKernelGGL((k_part<CH>), dim3(nch), dim3(256), 0, stream,
                       src, dstv, bcur, pairs, E, NB);
    hipLaunchKernelGGL(k_bucket, dim3(NB), dim3(1024), 0, stream,
                       pairs, boff, row_off, dinv, esrc, N, NB, E);

    const int gemm_blocks = (N + 127) / 128;
    const int agg_blocks  = (N + 3) / 4;   // 4 waves / block

    // --- layer 1: 256 -> 64 ---  (G overwrites pairs; pairs dead after k_bucket)
    hipLaunchKernelGGL((k_gemm_t<256, 64, 256>), dim3(gemm_blocks), dim3(256), 0, stream,
                       emb, 256, nodes, W1, dinv, G, N);
    hipLaunchKernelGGL((k_agg<64, 64>), dim3(agg_blocks), dim3(256), 0, stream,
                       row_off, esrc, (const uint*)G, dinv, b1, Xb, N);
    // --- layer 2: 64 -> 32 ---
    hipLaunchKernelGGL((k_gemm_t<64, 32, 128>), dim3(gemm_blocks), dim3(128), 0, stream,
                       Xb, 64, (const int*)nullptr, W2, dinv, G, N);
    hipLaunchKernelGGL((k_agg<32, 64>), dim3(agg_blocks), dim3(256), 0, stream,
                       row_off, esrc, (const uint*)G, dinv, b2, Xb, N);
    // --- layer 3: 32 -> 16 ---
    hipLaunchKernelGGL((k_gemm_t<32, 16, 64>), dim3(gemm_blocks), dim3(64), 0, stream,
                       Xb, 64, (const int*)nullptr, W3, dinv, G, N);
    hipLaunchKernelGGL((k_agg<16, 16>), dim3(agg_blocks), dim3(256), 0, stream,
                       row_off, esrc, (const uint*)G, dinv, b3, out, N);
}

// Round 5
// 318.672 us; speedup vs baseline: 6.2331x; 1.2121x over previous
//
#include <hip/hip_runtime.h>

// ---------------------------------------------------------------------------
// 3-layer GCN forward. out[d] = relu( dinv[d]*( sum_{s->d} g[s] + g[d] ) + b ),
// g = (x@W)*dinv stored bf16 (halves random-gather traffic; f32 accum).
// GEMMs: split-bf16 MFMA (x = hi+lo, 3 MFMA passes => ~f32 accuracy).
// CSR built per call via two-level counting sort (bucket = dst>>9), packed u32.
// ---------------------------------------------------------------------------

#define BSH 9                 // 512 nodes per bucket
#define BNODES (1 << BSH)

typedef __attribute__((ext_vector_type(8))) short bf16x8;
typedef __attribute__((ext_vector_type(4))) float f32x4;

__device__ inline ushort f2bf(float x) {   // round-to-nearest-even f32->bf16
    uint u = __float_as_uint(x);
    return (ushort)((u + 0x7fffu + ((u >> 16) & 1u)) >> 16);
}
__device__ inline float bf2f(ushort h) { return __uint_as_float(((uint)h) << 16); }
__device__ inline void split2(float x, ushort& h, ushort& l) {
    ushort hh = f2bf(x);
    h = hh;
    l = f2bf(x - bf2f(hh));
}

__global__ void k_zero_i(int* __restrict__ p, int n) {
    int i = blockIdx.x * blockDim.x + threadIdx.x;
    if (i < n) p[i] = 0;
}

// bucket histogram of dst
__global__ __launch_bounds__(256) void k_bhist(const int* __restrict__ dst,
                                               int* __restrict__ bcnt, int E) {
    __shared__ int h[256];
    int t = threadIdx.x;
    h[t] = 0;
    __syncthreads();
    for (int i = blockIdx.x * 256 + t; i < E; i += gridDim.x * 256)
        atomicAdd(&h[dst[i] >> BSH], 1);
    __syncthreads();
    if (h[t]) atomicAdd(&bcnt[t], h[t]);
}

// scan bucket counts -> boff (exclusive), init bcur. NB <= 1024.
__global__ __launch_bounds__(1024) void k_bscan(const int* __restrict__ bcnt,
                                                int* __restrict__ boff,
                                                int* __restrict__ bcur, int NB) {
    __shared__ int s[1024];
    int t = threadIdx.x;
    int v = (t < NB) ? bcnt[t] : 0;
    s[t] = v;
    __syncthreads();
    for (int off = 1; off < 1024; off <<= 1) {
        int a = (t >= off) ? s[t - off] : 0;
        __syncthreads();
        s[t] += a;
        __syncthreads();
    }
    if (t < NB) {
        int ex = s[t] - v;
        boff[t] = ex;
        bcur[t] = ex;
    }
    if (t == NB - 1) boff[NB] = s[t];
}

// partition edges into bucket-contiguous packed (local_dst<<23 | src) words
template <int CH>
__global__ __launch_bounds__(256) void k_part(const int* __restrict__ src,
                                              const int* __restrict__ dst,
                                              int* __restrict__ bcur,
                                              uint* __restrict__ pairs,
                                              int E, int NB) {
    __shared__ int lh[256];
    __shared__ int lbase[256];
    const int t = threadIdx.x;
    const int e0 = blockIdx.x * CH;
    const int n = min(CH, E - e0);

    lh[t] = 0;
    __syncthreads();
    for (int i = t; i < n; i += 256) atomicAdd(&lh[dst[e0 + i] >> BSH], 1);
    __syncthreads();
    if (t < NB && lh[t] > 0) lbase[t] = atomicAdd(&bcur[t], lh[t]);
    __syncthreads();
    lh[t] = 0;
    __syncthreads();
    for (int i = t; i < n; i += 256) {
        int d = dst[e0 + i];
        int b = d >> BSH;
        int r = atomicAdd(&lh[b], 1);
        pairs[(long)lbase[b] + r] = ((uint)(d & (BNODES - 1)) << 23) | (uint)src[e0 + i];
    }
}

// per-bucket: per-node histogram + scan (LDS), emit row_off/dinv, scatter esrc
__global__ __launch_bounds__(1024) void k_bucket(const uint* __restrict__ pairs,
                                                 const int* __restrict__ boff,
                                                 int* __restrict__ row_off,
                                                 float* __restrict__ dinv,
                                                 int* __restrict__ esrc,
                                                 int N, int NB, int E) {
    __shared__ int cnt[BNODES];
    __shared__ int sc[BNODES];
    __shared__ int cur[BNODES];
    const int b = blockIdx.x;
    const int t = threadIdx.x;
    const int base = b << BSH;
    const int nn = min(BNODES, N - base);
    const int ebase = boff[b], eend = boff[b + 1];

    if (t < BNODES) cnt[t] = 0;
    __syncthreads();
    for (int e = ebase + t; e < eend; e += 1024)
        atomicAdd(&cnt[pairs[e] >> 23], 1);
    __syncthreads();
    if (t < BNODES) sc[t] = cnt[t];
    __syncthreads();
    for (int off = 1; off < BNODES; off <<= 1) {
        int a = (t < BNODES && t >= off) ? sc[t - off] : 0;
        __syncthreads();
        if (t < BNODES) sc[t] += a;
        __syncthreads();
    }
    if (t < nn) {
        int ex = sc[t] - cnt[t];
        row_off[base + t] = ebase + ex;
        cur[t] = ex;
        dinv[base + t] = rsqrtf((float)(cnt[t] + 1));
    }
    if (b == NB - 1 && t == 0) row_off[N] = E;
    __syncthreads();
    for (int e = ebase + t; e < eend; e += 1024) {
        uint p = pairs[e];
        int r = atomicAdd(&cur[p >> 23], 1);
        esrc[ebase + r] = (int)(p & 0x7fffffu);
    }
}

// split W[K][OF] f32 -> Whi/Wlo [OF][K] bf16 (transposed), all 3 layers
__global__ void k_prepW(const float* __restrict__ W1, const float* __restrict__ W2,
                        const float* __restrict__ W3,
                        ushort* __restrict__ Wh1, ushort* __restrict__ Wl1,
                        ushort* __restrict__ Wh2, ushort* __restrict__ Wl2,
                        ushort* __restrict__ Wh3, ushort* __restrict__ Wl3) {
    int i = blockIdx.x * 256 + threadIdx.x;
    ushort h, l;
    if (i < 16384) {                       // L1: 256x64
        int k = i >> 6, n = i & 63;
        split2(W1[i], h, l);
        Wh1[n * 256 + k] = h; Wl1[n * 256 + k] = l;
    } else if (i < 16384 + 2048) {         // L2: 64x32
        int j = i - 16384;
        int k = j >> 5, n = j & 31;
        split2(W2[j], h, l);
        Wh2[n * 64 + k] = h; Wl2[n * 64 + k] = l;
    } else if (i < 16384 + 2048 + 512) {   // L3: 32x16
        int j = i - 18432;
        int k = j >> 4, n = j & 15;
        split2(W3[j], h, l);
        Wh3[n * 32 + k] = h; Wl3[n * 32 + k] = l;
    }
}

// ---------------------------------------------------------------------------
// Split-bf16 MFMA GEMM: G[n][0..OF) = bf16( (X[row(n)] @ W) * dinv[n] ).
// Block = 64 rows x OF cols, 4 waves (16 rows each), BK=32 per step.
// LDS frags k-contiguous, rows padded to 40 bf16 (2-way bank alias only).
// acc = Ahi*Bhi + Ahi*Blo + Alo*Bhi  (lo*lo dropped; rel err ~2^-17).
// ---------------------------------------------------------------------------
template <int K, int OF>
__global__ __launch_bounds__(256) void k_mfma(
    const float* __restrict__ X, int sx,
    const int* __restrict__ nodes,          // may be null (identity)
    const ushort* __restrict__ Wh,          // [OF][K] bf16
    const ushort* __restrict__ Wl,
    const float* __restrict__ dinv,
    ushort* __restrict__ G,                 // bf16, packed stride OF
    int N)
{
    constexpr int BM = 64, BK = 32, LDF = 40;
    constexpr int NT = OF / 16;             // MFMA col tiles
    __shared__ ushort Ah[BM * LDF], Al[BM * LDF];
    __shared__ ushort Bh[OF * LDF], Bl[OF * LDF];

    const int tid = threadIdx.x;
    const int l = tid & 63;
    const int w = tid >> 6;                 // wave id: rows w*16..w*16+15
    const int m0 = blockIdx.x * BM;
    const int lm = l & 15, kg = l >> 4;

    f32x4 acc[NT];
#pragma unroll
    for (int nt = 0; nt < NT; ++nt) acc[nt] = (f32x4){0.f, 0.f, 0.f, 0.f};

    for (int k0 = 0; k0 < K; k0 += BK) {
        __syncthreads();
        // stage A: 64 rows x 32 k (f32 -> hi/lo bf16)
#pragma unroll
        for (int t = 0; t < 2; ++t) {
            int i = tid + t * 256;
            int m = i >> 3, kq = i & 7;
            float4 v = make_float4(0.f, 0.f, 0.f, 0.f);
            if (m0 + m < N) {
                long row = nodes ? (long)nodes[m0 + m] : (long)(m0 + m);
                v = *reinterpret_cast<const float4*>(X + row * (long)sx + k0 + kq * 4);
            }
            ushort4 hh, ll;
            split2(v.x, hh.x, ll.x); split2(v.y, hh.y, ll.y);
            split2(v.z, hh.z, ll.z); split2(v.w, hh.w, ll.w);
            *reinterpret_cast<ushort4*>(&Ah[m * LDF + kq * 4]) = hh;
            *reinterpret_cast<ushort4*>(&Al[m * LDF + kq * 4]) = ll;
        }
        // stage B: OF rows x 32 k from pre-split W (k-contiguous)
        for (int i = tid; i < OF * 16; i += 256) {
            int n = i >> 4, ku = i & 15;
            *reinterpret_cast<uint*>(&Bh[n * LDF + ku * 2]) =
                *reinterpret_cast<const uint*>(Wh + (long)n * K + k0 + ku * 2);
            *reinterpret_cast<uint*>(&Bl[n * LDF + ku * 2]) =
                *reinterpret_cast<const uint*>(Wl + (long)n * K + k0 + ku * 2);
        }
        __syncthreads();

        bf16x8 ah = *reinterpret_cast<bf16x8*>(&Ah[(w * 16 + lm) * LDF + kg * 8]);
        bf16x8 al = *reinterpret_cast<bf16x8*>(&Al[(w * 16 + lm) * LDF + kg * 8]);
#pragma unroll
        for (int nt = 0; nt < NT; ++nt) {
            bf16x8 bh = *reinterpret_cast<bf16x8*>(&Bh[(nt * 16 + lm) * LDF + kg * 8]);
            bf16x8 bl = *reinterpret_cast<bf16x8*>(&Bl[(nt * 16 + lm) * LDF + kg * 8]);
            acc[nt] = __builtin_amdgcn_mfma_f32_16x16x32_bf16(al, bh, acc[nt], 0, 0, 0);
            acc[nt] = __builtin_amdgcn_mfma_f32_16x16x32_bf16(ah, bl, acc[nt], 0, 0, 0);
            acc[nt] = __builtin_amdgcn_mfma_f32_16x16x32_bf16(ah, bh, acc[nt], 0, 0, 0);
        }
    }
    // epilogue: D[row=(l>>4)*4+r][col=lm] per tile; scale dinv, cvt bf16
#pragma unroll
    for (int r = 0; r < 4; ++r) {
        int m = m0 + w * 16 + kg * 4 + r;
        if (m < N) {
            float dv = dinv[m];
#pragma unroll
            for (int nt = 0; nt < NT; ++nt)
                G[(long)m * OF + nt * 16 + lm] = f2bf(acc[nt][r] * dv);
        }
    }
}

// ---------------------------------------------------------------------------
// CSR aggregation (bf16 uint2 gather, f32 accum) + self-loop + epilogue.
// One wave per node; OF/4 lanes per edge (each lane one uint2 = 4 bf16).
// ---------------------------------------------------------------------------
template <int OF, int OSTRIDE>
__global__ __launch_bounds__(256) void k_agg(
    const int* __restrict__ row_off, const int* __restrict__ esrc,
    const uint2* __restrict__ g,     // row = OF/4 uint2
    const float* __restrict__ dinv, const float* __restrict__ b,
    float* __restrict__ y, int N)
{
    constexpr int WPE = OF / 4;      // lanes per edge
    constexpr int EPW = 64 / WPE;    // edges in parallel
    const int lane = threadIdx.x & 63;
    const int q = lane % WPE;        // feature quad
    const int sub = lane / WPE;
    const int n = blockIdx.x * (blockDim.x >> 6) + (threadIdx.x >> 6);
    if (n >= N) return;
    const int start = row_off[n], end = row_off[n + 1];

    float4 ac[4];
#pragma unroll
    for (int u = 0; u < 4; ++u) ac[u] = make_float4(0.f, 0.f, 0.f, 0.f);

    int e = start + sub;
    for (; e + 3 * EPW < end; e += 4 * EPW) {
        int s0 = esrc[e];
        int s1 = esrc[e + EPW];
        int s2 = esrc[e + 2 * EPW];
        int s3 = esrc[e + 3 * EPW];
        uint2 w0 = g[(long)s0 * WPE + q];
        uint2 w1 = g[(long)s1 * WPE + q];
        uint2 w2 = g[(long)s2 * WPE + q];
        uint2 w3 = g[(long)s3 * WPE + q];
        ac[0].x += __uint_as_float(w0.x << 16); ac[0].y += __uint_as_float(w0.x & 0xffff0000u);
        ac[0].z += __uint_as_float(w0.y << 16); ac[0].w += __uint_as_float(w0.y & 0xffff0000u);
        ac[1].x += __uint_as_float(w1.x << 16); ac[1].y += __uint_as_float(w1.x & 0xffff0000u);
        ac[1].z += __uint_as_float(w1.y << 16); ac[1].w += __uint_as_float(w1.y & 0xffff0000u);
        ac[2].x += __uint_as_float(w2.x << 16); ac[2].y += __uint_as_float(w2.x & 0xffff0000u);
        ac[2].z += __uint_as_float(w2.y << 16); ac[2].w += __uint_as_float(w2.y & 0xffff0000u);
        ac[3].x += __uint_as_float(w3.x << 16); ac[3].y += __uint_as_float(w3.x & 0xffff0000u);
        ac[3].z += __uint_as_float(w3.y << 16); ac[3].w += __uint_as_float(w3.y & 0xffff0000u);
    }
    for (; e < end; e += EPW) {
        uint2 w = g[(long)esrc[e] * WPE + q];
        ac[0].x += __uint_as_float(w.x << 16); ac[0].y += __uint_as_float(w.x & 0xffff0000u);
        ac[0].z += __uint_as_float(w.y << 16); ac[0].w += __uint_as_float(w.y & 0xffff0000u);
    }
    float4 a;
    a.x = (ac[0].x + ac[1].x) + (ac[2].x + ac[3].x);
    a.y = (ac[0].y + ac[1].y) + (ac[2].y + ac[3].y);
    a.z = (ac[0].z + ac[1].z) + (ac[2].z + ac[3].z);
    a.w = (ac[0].w + ac[1].w) + (ac[2].w + ac[3].w);
#pragma unroll
    for (int m = WPE; m < 64; m <<= 1) {
        a.x += __shfl_xor(a.x, m, 64);
        a.y += __shfl_xor(a.y, m, 64);
        a.z += __shfl_xor(a.z, m, 64);
        a.w += __shfl_xor(a.w, m, 64);
    }
    if (sub == 0) {
        uint2 sv = g[(long)n * WPE + q];   // self loop
        a.x += __uint_as_float(sv.x << 16); a.y += __uint_as_float(sv.x & 0xffff0000u);
        a.z += __uint_as_float(sv.y << 16); a.w += __uint_as_float(sv.y & 0xffff0000u);
        float dv = dinv[n];
        float4 bb = *reinterpret_cast<const float4*>(&b[q * 4]);
        float4 o;
        o.x = fmaxf(fmaf(a.x, dv, bb.x), 0.f);
        o.y = fmaxf(fmaf(a.y, dv, bb.y), 0.f);
        o.z = fmaxf(fmaf(a.z, dv, bb.z), 0.f);
        o.w = fmaxf(fmaf(a.w, dv, bb.w), 0.f);
        *reinterpret_cast<float4*>(&y[(long)n * OSTRIDE + q * 4]) = o;
    }
}

extern "C" void kernel_launch(void* const* d_in, const int* in_sizes, int n_in,
                              void* d_out, int out_size, void* d_ws, size_t ws_size,
                              hipStream_t stream) {
    const int*   nodes = (const int*)d_in[0];
    const int*   edges = (const int*)d_in[1];
    const float* emb   = (const float*)d_in[2];
    const float* W1    = (const float*)d_in[3];
    const float* b1    = (const float*)d_in[4];
    const float* W2    = (const float*)d_in[5];
    const float* b2    = (const float*)d_in[6];
    const float* W3    = (const float*)d_in[7];
    const float* b3    = (const float*)d_in[8];

    const int N = in_sizes[0];
    const int E = in_sizes[1] / 2;
    const int* src  = edges;
    const int* dstv = edges + E;
    const int NB = (N + BNODES - 1) >> BSH;   // 196 for N=100000

    char* ws = (char*)d_ws;
    size_t off = 0;
    auto alloc = [&](size_t bytes) {
        char* p = ws + off;
        off += (bytes + 255) & ~(size_t)255;
        return p;
    };
    float* dinv    = (float*)alloc((size_t)N * 4);
    int*   row_off = (int*)  alloc((size_t)(N + 1) * 4);
    int*   bcnt    = (int*)  alloc((size_t)(NB + 1) * 4);
    int*   boff    = (int*)  alloc((size_t)(NB + 1) * 4);
    int*   bcur    = (int*)  alloc((size_t)NB * 4);
    int*   esrc    = (int*)  alloc((size_t)E * 4);
    size_t shsz    = (size_t)E * 4 > (size_t)N * 128 ? (size_t)E * 4 : (size_t)N * 128;
    char*  shared_region = alloc(shsz);            // pairs u32 (12.8MB) / G bf16 (12.8MB)
    uint*  pairs   = (uint*)shared_region;
    ushort* G      = (ushort*)shared_region;
    float* Xb      = (float*)alloc((size_t)N * 64 * 4);
    ushort* Wh1 = (ushort*)alloc(16384 * 2), *Wl1 = (ushort*)alloc(16384 * 2);
    ushort* Wh2 = (ushort*)alloc(2048 * 2),  *Wl2 = (ushort*)alloc(2048 * 2);
    ushort* Wh3 = (ushort*)alloc(512 * 2),   *Wl3 = (ushort*)alloc(512 * 2);
    float* out     = (float*)d_out;

    // --- CSR build + dinv + W prep ---
    constexpr int CH = 4096;
    const int nch = (E + CH - 1) / CH;
    hipLaunchKernelGGL(k_zero_i, dim3((NB + 255) / 256), dim3(256), 0, stream, bcnt, NB);
    hipLaunchKernelGGL(k_bhist,  dim3(1024), dim3(256), 0, stream, dstv, bcnt, E);
    hipLaunchKernelGGL(k_bscan,  dim3(1), dim3(1024), 0, stream, bcnt, boff, bcur, NB);
    hipLaunchKernelGGL((k_part<CH>), dim3(nch), dim3(256), 0, stream,
                       src, dstv, bcur, pairs, E, NB);
    hipLaunchKernelGGL(k_bucket, dim3(NB), dim3(1024), 0, stream,
                       pairs, boff, row_off, dinv, esrc, N, NB, E);
    hipLaunchKernelGGL(k_prepW, dim3(74), dim3(256), 0, stream,
                       W1, W2, W3, Wh1, Wl1, Wh2, Wl2, Wh3, Wl3);

    const int gb = (N + 63) / 64;
    const int ab = (N + 3) / 4;   // 4 waves / block

    // --- layer 1: 256 -> 64 ---  (G overwrites pairs; pairs dead after k_bucket)
    hipLaunchKernelGGL((k_mfma<256, 64>), dim3(gb), dim3(256), 0, stream,
                       emb, 256, nodes, Wh1, Wl1, dinv, G, N);
    hipLaunchKernelGGL((k_agg<64, 64>), dim3(ab), dim3(256), 0, stream,
                       row_off, esrc, (const uint2*)G, dinv, b1, Xb, N);
    // --- layer 2: 64 -> 32 ---
    hipLaunchKernelGGL((k_mfma<64, 32>), dim3(gb), dim3(256), 0, stream,
                       Xb, 64, (const int*)nullptr, Wh2, Wl2, dinv, G, N);
    hipLaunchKernelGGL((k_agg<32, 64>), dim3(ab), dim3(256), 0, stream,
                       row_off, esrc, (const uint2*)G, dinv, b2, Xb, N);
    // --- layer 3: 32 -> 16 ---
    hipLaunchKernelGGL((k_mfma<32, 16>), dim3(gb), dim3(256), 0, stream,
                       Xb, 64, (const int*)nullptr, Wh3, Wl3, dinv, G, N);
    hipLaunchKernelGGL((k_agg<16, 16>), dim3(ab), dim3(256), 0, stream,
                       row_off, esrc, (const uint2*)G, dinv, b3, out, N);
}